// Round 1
// 423.835 us; speedup vs baseline: 1.0348x; 1.0348x over previous
//
#include <hip/hip_runtime.h>
#include <hip/hip_bf16.h>

#define NN 50000
#define NE 800000
#define NG 500
#define NF 128
#define NH 64
#define SCAN_B ((NN + 255)/256)   // 196

typedef unsigned int u32;
typedef unsigned short u16;
typedef _Float16 h2 __attribute__((ext_vector_type(2)));
typedef _Float16 h8 __attribute__((ext_vector_type(8)));   // MFMA A/B frag (4 VGPR)
typedef float f32x4 __attribute__((ext_vector_type(4)));   // MFMA acc

__device__ __forceinline__ float bf1(u16 v){ return __uint_as_float(((u32)v) << 16); }
__device__ __forceinline__ float h1(u16 v){ return (float)__builtin_bit_cast(_Float16, v); }
__device__ __forceinline__ u32 pk(float a, float b){
  return __builtin_bit_cast(u32, __builtin_amdgcn_cvt_pkrtz(a, b));
}
__device__ __forceinline__ h2 uph(u32 u){ return __builtin_bit_cast(h2, u); }
__device__ __forceinline__ u16 f16b(float f){ return __builtin_bit_cast(u16, (_Float16)f); }

// decode 8 f16 -> 8 f32
__device__ __forceinline__ void cv8h(uint4 q, float* f){
  h2 v0 = uph(q.x), v1 = uph(q.y), v2 = uph(q.z), v3 = uph(q.w);
  f[0]=(float)v0.x; f[1]=(float)v0.y; f[2]=(float)v1.x; f[3]=(float)v1.y;
  f[4]=(float)v2.x; f[5]=(float)v2.y; f[6]=(float)v3.x; f[7]=(float)v3.y;
}

__device__ __forceinline__ h8 pack8(float4 p, float4 q){
  uint4 t;
  t.x = pk(p.x, p.y); t.y = pk(p.z, p.w);
  t.z = pk(q.x, q.y); t.w = pk(q.z, q.w);
  return __builtin_bit_cast(h8, t);
}
__device__ __forceinline__ f32x4 z4(){
  f32x4 v; v[0]=0.f; v[1]=0.f; v[2]=0.f; v[3]=0.f; return v;
}

// ---- dtype probe (f32 inputs proven; kept as output-format hedge)
__global__ void k_detect(const u32* __restrict__ x, int* __restrict__ flag){
  int lane = threadIdx.x;
  u32 w = x[lane];
  u32 lo = w & 0xFFFFu;
  u32 e = (lo >> 7) & 0xFFu;
  bool vote = (e >= 0x60u && e <= 0x8Fu);
  unsigned long long m = __ballot(vote);
  if (lane == 0) flag[0] = (__popcll(m) >= 32) ? 1 : 0;
}

// ---- graph boundaries
__global__ void k_bounds(const int* __restrict__ batch, int* __restrict__ starts){
  int g = threadIdx.x;
  if (g > NG) return;
  int lo = 0, hi = NN;
  while (lo < hi){ int mid = (lo + hi) >> 1; if (batch[mid] < g) lo = mid + 1; else hi = mid; }
  starts[g] = lo;
}

// ---- weight prep: transpose to f16 B-fragment layout [col][k]
__global__ __launch_bounds__(256) void k_prep(const float* __restrict__ Wt,
    const float* __restrict__ W1, const float* __restrict__ W2,
    u16* __restrict__ wtT, u16* __restrict__ w1T, u16* __restrict__ w2T){
  int t = blockIdx.x*256 + threadIdx.x;
  if (t < NH*NF){                       // wtT[c][k] = Wt[k][c]
    int c = t >> 7, k = t & 127;
    wtT[t] = f16b(Wt[(size_t)k*NH + c]);
  }
  if (t < 3*NH*NH){                     // w{1,2}T[l][c][k] = W{1,2}[l][k][c]
    int l = t >> 12, c = (t >> 6) & 63, k = t & 63;
    w1T[t] = f16b(W1[(size_t)l*NH*NH + k*NH + c]);
    w2T[t] = f16b(W2[(size_t)l*NH*NH + k*NH + c]);
  }
}

// ---- CSR build: degree count
__global__ __launch_bounds__(256) void k_count(const int* __restrict__ ei, int* __restrict__ deg){
  int e = blockIdx.x*256 + threadIdx.x;
  if (e >= NE) return;
  atomicAdd(&deg[ei[NE + e]], 1);
}

// ---- hierarchical coalesced scan (3 phases)
__global__ __launch_bounds__(256) void k_scanA(const int* __restrict__ deg, int* __restrict__ bsum){
  __shared__ int red[256];
  int t = threadIdx.x;
  int i = blockIdx.x*256 + t;
  red[t] = (i < NN) ? deg[i] : 0;
  __syncthreads();
  for (int off = 128; off > 0; off >>= 1){
    if (t < off) red[t] += red[t+off];
    __syncthreads();
  }
  if (t == 0) bsum[blockIdx.x] = red[0];
}

__global__ __launch_bounds__(256) void k_scanB(int* __restrict__ bsum){
  __shared__ int part[256];
  int t = threadIdx.x;
  int v = (t < SCAN_B) ? bsum[t] : 0;
  part[t] = v;
  __syncthreads();
  for (int off = 1; off < 256; off <<= 1){
    int u = (t >= off) ? part[t-off] : 0;
    __syncthreads();
    part[t] += u;
    __syncthreads();
  }
  if (t < SCAN_B) bsum[t] = part[t] - v;   // exclusive
}

__global__ __launch_bounds__(256) void k_scanC(const int* __restrict__ deg, const int* __restrict__ bsum,
    int* __restrict__ rowptr, int* __restrict__ cursor){
  __shared__ int part[256];
  int t = threadIdx.x;
  int i = blockIdx.x*256 + t;
  int v = (i < NN) ? deg[i] : 0;
  part[t] = v;
  __syncthreads();
  for (int off = 1; off < 256; off <<= 1){
    int u = (t >= off) ? part[t-off] : 0;
    __syncthreads();
    part[t] += u;
    __syncthreads();
  }
  int ex = part[t] - v + bsum[blockIdx.x];
  if (i < NN){ rowptr[i] = ex; cursor[i] = ex; }
  if (blockIdx.x == 0 && t == 0) rowptr[NN] = NE;
}

// ---- CSR fill (1 edge/thread)
__global__ __launch_bounds__(256) void k_fill(const int* __restrict__ ei,
    int* __restrict__ cursor, int* __restrict__ csr){
  int e = blockIdx.x*256 + threadIdx.x;
  if (e >= NE) return;
  int dst = ei[NE + e];
  int slot = atomicAdd(&cursor[dst], 1);
  csr[slot] = ei[e];
}

// ---- gather (f16 h -> f16 U): 8-slot x 8-chunk + unroll x2; block 0 re-zeros s1/s2
__global__ __launch_bounds__(256) void k_gather(const u16* __restrict__ h,
    const int* __restrict__ rowptr, const int* __restrict__ csr, u16* __restrict__ Uh,
    float* __restrict__ s1){
  if (blockIdx.x == 0 && threadIdx.x < 128) s1[threadIdx.x] = 0.f;  // s1[0:64], s2[64:128]
  int wid = threadIdx.x >> 6, lane = threadIdx.x & 63;
  int node = blockIdx.x*4 + wid;
  if (node >= NN) return;
  int chunk = lane & 7, epar = lane >> 3;
  int beg = rowptr[node], en = rowptr[node+1];
  float acc[8] = {0.f,0.f,0.f,0.f,0.f,0.f,0.f,0.f};
  if (epar == 0){
    uint4 q = *(const uint4*)&h[(size_t)node*NH + chunk*8];
    cv8h(q, acc);
  }
  int j = beg + epar;
  for (; j + 8 < en; j += 16){            // 2 edges in flight per lane
    int src0 = csr[j];
    int src1 = csr[j+8];
    uint4 q0 = *(const uint4*)&h[(size_t)src0*NH + chunk*8];
    uint4 q1 = *(const uint4*)&h[(size_t)src1*NH + chunk*8];
    float f0[8], f1[8];
    cv8h(q0, f0);
    cv8h(q1, f1);
    #pragma unroll
    for (int i = 0; i < 8; i++) acc[i] += f0[i] + f1[i];
  }
  if (j < en){
    int src = csr[j];
    uint4 q = *(const uint4*)&h[(size_t)src*NH + chunk*8];
    float f[8]; cv8h(q, f);
    #pragma unroll
    for (int i = 0; i < 8; i++) acc[i] += f[i];
  }
  #pragma unroll
  for (int i = 0; i < 8; i++){
    acc[i] += __shfl_xor(acc[i], 8);
    acc[i] += __shfl_xor(acc[i], 16);
    acc[i] += __shfl_xor(acc[i], 32);
  }
  if (epar == 0){
    uint4 o;
    o.x = pk(acc[0], acc[1]); o.y = pk(acc[2], acc[3]);
    o.z = pk(acc[4], acc[5]); o.w = pk(acc[6], acc[7]);
    *(uint4*)&Uh[(size_t)node*NH + chunk*8] = o;
  }
}

// ---- transform via MFMA: T = x @ Wt + bt, f16 out, col-sums to s1/s2
// A-frags from global f32 x (cvt to f16), B-frags from prepped wtT (regs).
__global__ __launch_bounds__(256) void k_transform_m(const float* __restrict__ x,
    const u16* __restrict__ wtT, const float* __restrict__ bt,
    u16* __restrict__ th, float* __restrict__ s1, float* __restrict__ s2){
  __shared__ float sRed[8*NH];
  int tid = threadIdx.x;
  int w = tid >> 6, l = tid & 63;
  int lr = l & 15, kb = l >> 4;
  // B frags: lane holds col=16n+lr, k = 32*kk + 8*kb + e  (contiguous in wtT[c][k])
  h8 bf[4][4];
  #pragma unroll
  for (int n = 0; n < 4; n++)
    #pragma unroll
    for (int kk = 0; kk < 4; kk++)
      bf[n][kk] = *(const h8*)&wtT[(size_t)(16*n + lr)*NF + kk*32 + kb*8];
  int node0 = blockIdx.x*64 + w*16;     // this wave's 16 rows
  int rowA = node0 + lr; if (rowA > NN-1) rowA = NN-1;
  const float* xr = x + (size_t)rowA*NF + kb*8;
  f32x4 acc[4];
  #pragma unroll
  for (int n = 0; n < 4; n++) acc[n] = z4();
  #pragma unroll
  for (int kk = 0; kk < 4; kk++){
    float4 p = *(const float4*)(xr + kk*32);
    float4 q = *(const float4*)(xr + kk*32 + 4);
    h8 a = pack8(p, q);
    #pragma unroll
    for (int n = 0; n < 4; n++)
      acc[n] = __builtin_amdgcn_mfma_f32_16x16x32_f16(a, bf[n][kk], acc[n], 0, 0, 0);
  }
  // D layout: col = 16n+lr, row = node0 + 4*kb + r
  #pragma unroll
  for (int n = 0; n < 4; n++){
    float bias = bt[16*n + lr];
    float a1 = 0.f, a2 = 0.f;
    #pragma unroll
    for (int r = 0; r < 4; r++){
      int g = node0 + 4*kb + r;
      float v = acc[n][r] + bias;
      if (g < NN){
        th[(size_t)g*NH + 16*n + lr] = f16b(v);
        a1 += v; a2 += v*v;
      }
    }
    a1 += __shfl_xor(a1, 16); a1 += __shfl_xor(a1, 32);
    a2 += __shfl_xor(a2, 16); a2 += __shfl_xor(a2, 32);
    if (kb == 0){
      sRed[w*NH + 16*n + lr] = a1;
      sRed[(4+w)*NH + 16*n + lr] = a2;
    }
  }
  __syncthreads();
  if (tid < NH){
    float a1 = sRed[tid] + sRed[NH+tid] + sRed[2*NH+tid] + sRed[3*NH+tid];
    float a2 = sRed[4*NH+tid] + sRed[5*NH+tid] + sRed[6*NH+tid] + sRed[7*NH+tid];
    unsafeAtomicAdd(&s1[tid], a1);
    unsafeAtomicAdd(&s2[tid], a2);
  }
}

// ---- MLP via MFMA: T = relu(relu(U@W1)@W2); V transposed through swizzled LDS
__global__ __launch_bounds__(256) void k_mlp_m(const u16* __restrict__ Uh, u16* __restrict__ Th,
    const u16* __restrict__ w1T, const u16* __restrict__ w2T, int wofs,
    float* __restrict__ s1, float* __restrict__ s2){
  __shared__ __align__(16) u16 sV[64*NH];   // 8 KB, XOR-swizzled granules
  __shared__ float sRed[8*NH];
  int tid = threadIdx.x;
  int w = tid >> 6, l = tid & 63;
  int lr = l & 15, kb = l >> 4;
  h8 b1[4][2], b2[4][2];
  #pragma unroll
  for (int n = 0; n < 4; n++)
    #pragma unroll
    for (int kk = 0; kk < 2; kk++){
      b1[n][kk] = *(const h8*)&w1T[wofs + (16*n + lr)*NH + kk*32 + kb*8];
      b2[n][kk] = *(const h8*)&w2T[wofs + (16*n + lr)*NH + kk*32 + kb*8];
    }
  int node0 = blockIdx.x*64;
  int rowA = node0 + 16*w + lr; if (rowA > NN-1) rowA = NN-1;
  f32x4 acc[4];
  #pragma unroll
  for (int n = 0; n < 4; n++) acc[n] = z4();
  #pragma unroll
  for (int kk = 0; kk < 2; kk++){
    h8 a = *(const h8*)&Uh[(size_t)rowA*NH + kk*32 + kb*8];
    #pragma unroll
    for (int n = 0; n < 4; n++)
      acc[n] = __builtin_amdgcn_mfma_f32_16x16x32_f16(a, b1[n][kk], acc[n], 0, 0, 0);
  }
  // relu(V) -> LDS in A-layout-friendly swizzle: idx = row*64 + (col ^ ((row&7)<<3))
  #pragma unroll
  for (int n = 0; n < 4; n++){
    #pragma unroll
    for (int r = 0; r < 4; r++){
      int row = 16*w + 4*kb + r;
      int col = 16*n + lr;
      sV[row*NH + (col ^ ((row & 7) << 3))] = f16b(fmaxf(acc[n][r], 0.f));
    }
  }
  __syncthreads();
  f32x4 acc2[4];
  #pragma unroll
  for (int n = 0; n < 4; n++) acc2[n] = z4();
  int rv = 16*w + lr;
  const u16* vrow = sV + rv*NH;
  #pragma unroll
  for (int kk = 0; kk < 2; kk++){
    h8 a = *(const h8*)&vrow[(kk*32 + kb*8) ^ ((rv & 7) << 3)];
    #pragma unroll
    for (int n = 0; n < 4; n++)
      acc2[n] = __builtin_amdgcn_mfma_f32_16x16x32_f16(a, b2[n][kk], acc2[n], 0, 0, 0);
  }
  #pragma unroll
  for (int n = 0; n < 4; n++){
    float a1 = 0.f, a2 = 0.f;
    #pragma unroll
    for (int r = 0; r < 4; r++){
      int g = node0 + 16*w + 4*kb + r;
      float v = fmaxf(acc2[n][r], 0.f);
      if (g < NN){
        Th[(size_t)g*NH + 16*n + lr] = f16b(v);
        a1 += v; a2 += v*v;
      }
    }
    a1 += __shfl_xor(a1, 16); a1 += __shfl_xor(a1, 32);
    a2 += __shfl_xor(a2, 16); a2 += __shfl_xor(a2, 32);
    if (kb == 0){
      sRed[w*NH + 16*n + lr] = a1;
      sRed[(4+w)*NH + 16*n + lr] = a2;
    }
  }
  __syncthreads();
  if (tid < NH){
    float a1 = sRed[tid] + sRed[NH+tid] + sRed[2*NH+tid] + sRed[3*NH+tid];
    float a2 = sRed[4*NH+tid] + sRed[5*NH+tid] + sRed[6*NH+tid] + sRed[7*NH+tid];
    unsafeAtomicAdd(&s1[tid], a1);
    unsafeAtomicAdd(&s2[tid], a2);
  }
}

// ---- per-graph embed with fused BN-fold; reads f16 t, writes h as f16
__global__ __launch_bounds__(256) void k_embed(const u16* __restrict__ t,
    const float* __restrict__ s1, const float* __restrict__ s2,
    const void* __restrict__ gamma, const void* __restrict__ beta, int ofs,
    u16* __restrict__ h, int write_h,
    const int* __restrict__ starts, const int* __restrict__ flag,
    void* __restrict__ dout, int layer){
  __shared__ float sRed[8*NH];
  int g = blockIdx.x;
  int tx = threadIdx.x & 63, ty = threadIdx.x >> 6;
  int bf = flag[0];
  float gm = bf ? bf1(((const u16*)gamma)[ofs+tx]) : ((const float*)gamma)[ofs+tx];
  float be = bf ? bf1(((const u16*)beta)[ofs+tx])  : ((const float*)beta)[ofs+tx];
  float mean = s1[tx] * (1.f/NN);
  float var  = s2[tx] * (1.f/NN) - mean*mean;
  float rr = rsqrtf(fmaxf(var, 0.f) + 1e-5f);
  float sc = gm * rr;
  float sh = be - mean*sc;
  int st = starts[g], en = starts[g+1];
  float ls1 = 0.f, ls2 = 0.f;
  if (write_h){
    for (int n = st + ty; n < en; n += 4){
      float z = h1(t[(size_t)n*NH + tx]) * sc + sh;
      h[(size_t)n*NH + tx] = f16b(z);
      ls1 += z; ls2 += z*z;
    }
  } else {
    for (int n = st + ty; n < en; n += 4){
      float z = h1(t[(size_t)n*NH + tx]) * sc + sh;
      ls1 += z; ls2 += z*z;
    }
  }
  sRed[ty*NH + tx] = ls1;
  sRed[(4+ty)*NH + tx] = ls2;
  __syncthreads();
  if (ty == 0){
    float a1 = sRed[tx] + sRed[NH+tx] + sRed[2*NH+tx] + sRed[3*NH+tx];
    float a2 = sRed[4*NH+tx] + sRed[5*NH+tx] + sRed[6*NH+tx] + sRed[7*NH+tx];
    int cnt = en - st;
    float inv = 1.f / (float)max(cnt, 1);
    float m = a1 * inv;
    float vv = a2 * inv - m*m;
    float s = sqrtf(fmaxf(vv, 0.f));
    size_t eidx = ((size_t)layer*NG + g)*NH + tx;
    size_t sidx = (size_t)4*NG*NH + eidx;
    if (bf){
      ((__hip_bfloat16*)dout)[eidx] = __float2bfloat16(m);
      ((__hip_bfloat16*)dout)[sidx] = __float2bfloat16(s);
    } else {
      ((float*)dout)[eidx] = m;
      ((float*)dout)[sidx] = s;
    }
  }
}

extern "C" void kernel_launch(void* const* d_in, const int* in_sizes, int n_in,
                              void* d_out, int out_size, void* d_ws, size_t ws_size,
                              hipStream_t stream) {
  const void* x    = d_in[0];
  const int* ei    = (const int*)d_in[1];
  const int* batch = (const int*)d_in[2];
  const void* Wt   = d_in[3];
  const void* bt   = d_in[4];
  const void* g0   = d_in[5];
  const void* b0   = d_in[6];
  const void* W1   = d_in[7];
  const void* W2   = d_in[8];
  const void* gs   = d_in[9];
  const void* bs   = d_in[10];

  u16*  hbuf = (u16*)d_ws;                      // NN*NH f16
  u16*  uh16 = hbuf + (size_t)NN*NH;            // NN*NH f16
  u16*  tb16 = uh16 + (size_t)NN*NH;            // NN*NH f16 (t, f16 end-to-end)
  float* s1   = (float*)d_ws + 2*(size_t)NN*NH; // 64 (after 2 f32-slots worth of f16)
  float* s2   = s1 + NH;                        // 64
  float* pad  = s2 + NH;                        // 128 (layout spacer)
  int* starts = (int*)(pad + 2*NH);             // 512
  int* flag   = starts + 512;                   // 64 (padded)
  int* deg    = flag + 64;                      // NN
  int* rowptr = deg + NN;                       // NN+64
  int* cursor = rowptr + NN + 64;               // NN
  int* csr    = cursor + NN;                    // NE
  int* bsum   = csr + NE;                       // 256
  u16* wtT    = (u16*)(bsum + 256);             // NH*NF f16 (16 KB), 16B-aligned
  u16* w1T    = wtT + (size_t)NH*NF;            // 3*NH*NH f16 (24 KB)
  u16* w2T    = w1T + (size_t)3*NH*NH;          // 3*NH*NH f16 (24 KB)

  hipMemsetAsync(s1, 0, 2*NH*sizeof(float), stream);
  hipMemsetAsync(deg, 0, NN*sizeof(int), stream);
  k_detect<<<1, 64, 0, stream>>>((const u32*)x, flag);
  k_bounds<<<1, 512, 0, stream>>>(batch, starts);
  k_prep<<<48, 256, 0, stream>>>((const float*)Wt, (const float*)W1, (const float*)W2, wtT, w1T, w2T);
  k_count<<<(NE+255)/256, 256, 0, stream>>>(ei, deg);
  k_scanA<<<SCAN_B, 256, 0, stream>>>(deg, bsum);
  k_scanB<<<1, 256, 0, stream>>>(bsum);
  k_scanC<<<SCAN_B, 256, 0, stream>>>(deg, bsum, rowptr, cursor);
  k_fill<<<(NE+255)/256, 256, 0, stream>>>(ei, cursor, csr);

  k_transform_m<<<(NN+63)/64, 256, 0, stream>>>((const float*)x, wtT, (const float*)bt, tb16, s1, s2);
  k_embed<<<NG, 256, 0, stream>>>(tb16, s1, s2, g0, b0, 0, hbuf, 1, starts, flag, d_out, 0);

  for (int l = 0; l < 3; l++){
    k_gather<<<(NN+3)/4, 256, 0, stream>>>(hbuf, rowptr, csr, uh16, s1);  // also zeros s1/s2
    k_mlp_m<<<(NN+63)/64, 256, 0, stream>>>(uh16, tb16, w1T, w2T, l*NH*NH, s1, s2);
    k_embed<<<NG, 256, 0, stream>>>(tb16, s1, s2, gs, bs, l*NH, hbuf, (l < 2) ? 1 : 0, starts, flag, d_out, l+1);
  }
}

// Round 2
// 366.638 us; speedup vs baseline: 1.1963x; 1.1560x over previous
//
#include <hip/hip_runtime.h>
#include <hip/hip_bf16.h>

#define NN 50000
#define NE 800000
#define NG 500
#define NF 128
#define NH 64
#define NB 256            // node buckets
#define NPB 196           // nodes per bucket: 256*196 = 50176 >= NN
#define EPB 4096          // edges per block (hist/scatter)
#define NBLK ((NE + EPB - 1)/EPB)   // 196

typedef unsigned int u32;
typedef unsigned short u16;
typedef _Float16 h2 __attribute__((ext_vector_type(2)));
typedef _Float16 h8 __attribute__((ext_vector_type(8)));   // MFMA A/B frag (4 VGPR)
typedef float f32x4 __attribute__((ext_vector_type(4)));   // MFMA acc

__device__ __forceinline__ float bf1(u16 v){ return __uint_as_float(((u32)v) << 16); }
__device__ __forceinline__ float h1(u16 v){ return (float)__builtin_bit_cast(_Float16, v); }
__device__ __forceinline__ u32 pk(float a, float b){
  return __builtin_bit_cast(u32, __builtin_amdgcn_cvt_pkrtz(a, b));
}
__device__ __forceinline__ h2 uph(u32 u){ return __builtin_bit_cast(h2, u); }
__device__ __forceinline__ u16 f16b(float f){ return __builtin_bit_cast(u16, (_Float16)f); }

// decode 8 f16 -> 8 f32
__device__ __forceinline__ void cv8h(uint4 q, float* f){
  h2 v0 = uph(q.x), v1 = uph(q.y), v2 = uph(q.z), v3 = uph(q.w);
  f[0]=(float)v0.x; f[1]=(float)v0.y; f[2]=(float)v1.x; f[3]=(float)v1.y;
  f[4]=(float)v2.x; f[5]=(float)v2.y; f[6]=(float)v3.x; f[7]=(float)v3.y;
}

__device__ __forceinline__ h8 pack8(float4 p, float4 q){
  uint4 t;
  t.x = pk(p.x, p.y); t.y = pk(p.z, p.w);
  t.z = pk(q.x, q.y); t.w = pk(q.z, q.w);
  return __builtin_bit_cast(h8, t);
}
__device__ __forceinline__ f32x4 z4(){
  f32x4 v; v[0]=0.f; v[1]=0.f; v[2]=0.f; v[3]=0.f; return v;
}

// ---- dtype probe (f32 inputs proven; kept as output-format hedge)
__global__ void k_detect(const u32* __restrict__ x, int* __restrict__ flag){
  int lane = threadIdx.x;
  u32 w = x[lane];
  u32 lo = w & 0xFFFFu;
  u32 e = (lo >> 7) & 0xFFu;
  bool vote = (e >= 0x60u && e <= 0x8Fu);
  unsigned long long m = __ballot(vote);
  if (lane == 0) flag[0] = (__popcll(m) >= 32) ? 1 : 0;
}

// ---- graph boundaries
__global__ void k_bounds(const int* __restrict__ batch, int* __restrict__ starts){
  int g = threadIdx.x;
  if (g > NG) return;
  int lo = 0, hi = NN;
  while (lo < hi){ int mid = (lo + hi) >> 1; if (batch[mid] < g) lo = mid + 1; else hi = mid; }
  starts[g] = lo;
}

// ---- weight prep: transpose to f16 B-fragment layout [col][k]
__global__ __launch_bounds__(256) void k_prep(const float* __restrict__ Wt,
    const float* __restrict__ W1, const float* __restrict__ W2,
    u16* __restrict__ wtT, u16* __restrict__ w1T, u16* __restrict__ w2T){
  int t = blockIdx.x*256 + threadIdx.x;
  if (t < NH*NF){                       // wtT[c][k] = Wt[k][c]
    int c = t >> 7, k = t & 127;
    wtT[t] = f16b(Wt[(size_t)k*NH + c]);
  }
  if (t < 3*NH*NH){                     // w{1,2}T[l][c][k] = W{1,2}[l][k][c]
    int l = t >> 12, c = (t >> 6) & 63, k = t & 63;
    w1T[t] = f16b(W1[(size_t)l*NH*NH + k*NH + c]);
    w2T[t] = f16b(W2[(size_t)l*NH*NH + k*NH + c]);
  }
}

// ==== bucketed CSR build (replaces count/scanA/scanB/scanC/fill) ====

// phase 1: per-bucket edge counts
__global__ __launch_bounds__(256) void k_bhist(const int* __restrict__ ei, int* __restrict__ bcount){
  __shared__ int h[NB];
  int tid = threadIdx.x;
  h[tid] = 0;
  __syncthreads();
  int e0 = blockIdx.x*EPB;
  #pragma unroll
  for (int i = 0; i < 16; i++){
    int e = e0 + i*256 + tid;
    if (e < NE) atomicAdd(&h[ei[NE + e] / NPB], 1);
  }
  __syncthreads();
  if (h[tid]) atomicAdd(&bcount[tid], h[tid]);
}

// phase 2: scan bucket counts -> region starts + working cursors
__global__ __launch_bounds__(256) void k_bscan(const int* __restrict__ bcount,
    int* __restrict__ bstart, int* __restrict__ bcur){
  __shared__ int part[NB];
  int t = threadIdx.x;
  int v = bcount[t];
  part[t] = v;
  __syncthreads();
  for (int off = 1; off < 256; off <<= 1){
    int u = (t >= off) ? part[t-off] : 0;
    __syncthreads();
    part[t] += u;
    __syncthreads();
  }
  int ex = part[t] - v;
  bstart[t] = ex;
  bcur[t] = ex;
  if (t == 0) bstart[NB] = NE;
}

// phase 3: bucket-clustered scatter of packed edges (dst<<16 | src; both < 65536)
__global__ __launch_bounds__(256) void k_bscat(const int* __restrict__ ei,
    int* __restrict__ bcur, u32* __restrict__ pkE){
  __shared__ int h[NB];
  __shared__ int base[NB];
  int tid = threadIdx.x;
  h[tid] = 0;
  __syncthreads();
  int e0 = blockIdx.x*EPB;
  u32 meta[16], val[16];
  #pragma unroll
  for (int i = 0; i < 16; i++){
    int e = e0 + i*256 + tid;
    if (e < NE){
      int s = ei[e], d = ei[NE + e];
      int b = d / NPB;
      int r = atomicAdd(&h[b], 1);           // rank within block's bucket group (<4096)
      meta[i] = ((u32)b << 16) | (u32)r;
      val[i]  = ((u32)d << 16) | (u32)s;
    } else meta[i] = 0xFFFFFFFFu;
  }
  __syncthreads();
  base[tid] = h[tid] ? atomicAdd(&bcur[tid], h[tid]) : 0;   // one atomic per (block,bucket)
  __syncthreads();
  #pragma unroll
  for (int i = 0; i < 16; i++){
    if (meta[i] != 0xFFFFFFFFu){
      int b = meta[i] >> 16, r = meta[i] & 0xFFFF;
      pkE[base[b] + r] = val[i];
    }
  }
}

// phase 4: per-bucket local CSR: LDS node-histogram + scan -> rowptr + dense csr
__global__ __launch_bounds__(256) void k_bfill(const u32* __restrict__ pkE,
    const int* __restrict__ bstart, int* __restrict__ rowptr, int* __restrict__ csr){
  __shared__ int part[NB];
  __shared__ int cur[NB];
  int b = blockIdx.x;
  int tid = threadIdx.x;
  int nb0 = b*NPB;
  int nr = min(NPB, NN - nb0);
  int rbeg = bstart[b], rend = bstart[b+1];
  part[tid] = 0;
  __syncthreads();
  for (int j = rbeg + tid; j < rend; j += 256){
    u32 pe = pkE[j];
    atomicAdd(&part[(int)(pe >> 16) - nb0], 1);
  }
  __syncthreads();
  int v = part[tid];
  __syncthreads();
  for (int off = 1; off < 256; off <<= 1){
    int u = (tid >= off) ? part[tid-off] : 0;
    __syncthreads();
    part[tid] += u;
    __syncthreads();
  }
  int ex = part[tid] - v;               // exclusive scan of per-node counts
  if (tid < nr) rowptr[nb0 + tid] = rbeg + ex;
  if (b == NB-1 && tid == 0) rowptr[NN] = NE;
  cur[tid] = ex;
  __syncthreads();
  for (int j = rbeg + tid; j < rend; j += 256){
    u32 pe = pkE[j];
    int node = (int)(pe >> 16) - nb0;
    int p = atomicAdd(&cur[node], 1);
    csr[rbeg + p] = (int)(pe & 0xFFFFu);   // dense, bucket-contiguous writes
  }
}

// ---- gather with fused BN affine: U = sc*(t_self + sum t_src) + (deg+1)*sh
__global__ __launch_bounds__(256) void k_gather(const u16* __restrict__ t,
    const int* __restrict__ rowptr, const int* __restrict__ csr, u16* __restrict__ Uh,
    const float* __restrict__ s1, const float* __restrict__ s2,
    const void* __restrict__ gamma, const void* __restrict__ beta, int ofs,
    const int* __restrict__ flag){
  __shared__ float scs[NH], shs[NH];
  int tid = threadIdx.x;
  if (tid < NH){
    int bf = flag[0];
    float gm = bf ? bf1(((const u16*)gamma)[ofs+tid]) : ((const float*)gamma)[ofs+tid];
    float be = bf ? bf1(((const u16*)beta)[ofs+tid])  : ((const float*)beta)[ofs+tid];
    float mean = s1[tid] * (1.f/NN);
    float var  = s2[tid] * (1.f/NN) - mean*mean;
    float rr = rsqrtf(fmaxf(var, 0.f) + 1e-5f);
    float sc = gm * rr;
    scs[tid] = sc;
    shs[tid] = be - mean*sc;
  }
  __syncthreads();
  int wid = tid >> 6, lane = tid & 63;
  int node = blockIdx.x*4 + wid;
  if (node >= NN) return;
  int chunk = lane & 7, epar = lane >> 3;
  int beg = rowptr[node], en = rowptr[node+1];
  float acc[8] = {0.f,0.f,0.f,0.f,0.f,0.f,0.f,0.f};
  if (epar == 0){
    uint4 q = *(const uint4*)&t[(size_t)node*NH + chunk*8];
    cv8h(q, acc);
  }
  int j = beg + epar;
  for (; j + 8 < en; j += 16){            // 2 edges in flight per lane
    int src0 = csr[j];
    int src1 = csr[j+8];
    uint4 q0 = *(const uint4*)&t[(size_t)src0*NH + chunk*8];
    uint4 q1 = *(const uint4*)&t[(size_t)src1*NH + chunk*8];
    float f0[8], f1[8];
    cv8h(q0, f0);
    cv8h(q1, f1);
    #pragma unroll
    for (int i = 0; i < 8; i++) acc[i] += f0[i] + f1[i];
  }
  if (j < en){
    int src = csr[j];
    uint4 q = *(const uint4*)&t[(size_t)src*NH + chunk*8];
    float f[8]; cv8h(q, f);
    #pragma unroll
    for (int i = 0; i < 8; i++) acc[i] += f[i];
  }
  #pragma unroll
  for (int i = 0; i < 8; i++){
    acc[i] += __shfl_xor(acc[i], 8);
    acc[i] += __shfl_xor(acc[i], 16);
    acc[i] += __shfl_xor(acc[i], 32);
  }
  if (epar == 0){
    float deg1 = (float)(en - beg + 1);
    float o[8];
    #pragma unroll
    for (int i = 0; i < 8; i++)
      o[i] = scs[chunk*8+i]*acc[i] + deg1*shs[chunk*8+i];
    uint4 ov;
    ov.x = pk(o[0], o[1]); ov.y = pk(o[2], o[3]);
    ov.z = pk(o[4], o[5]); ov.w = pk(o[6], o[7]);
    *(uint4*)&Uh[(size_t)node*NH + chunk*8] = ov;
  }
}

// ---- transform via MFMA: T = x @ Wt + bt, f16 out, col-sums to s1/s2
__global__ __launch_bounds__(256) void k_transform_m(const float* __restrict__ x,
    const u16* __restrict__ wtT, const float* __restrict__ bt,
    u16* __restrict__ th, float* __restrict__ s1, float* __restrict__ s2){
  __shared__ float sRed[8*NH];
  int tid = threadIdx.x;
  int w = tid >> 6, l = tid & 63;
  int lr = l & 15, kb = l >> 4;
  h8 bf[4][4];
  #pragma unroll
  for (int n = 0; n < 4; n++)
    #pragma unroll
    for (int kk = 0; kk < 4; kk++)
      bf[n][kk] = *(const h8*)&wtT[(size_t)(16*n + lr)*NF + kk*32 + kb*8];
  int node0 = blockIdx.x*64 + w*16;
  int rowA = node0 + lr; if (rowA > NN-1) rowA = NN-1;
  const float* xr = x + (size_t)rowA*NF + kb*8;
  f32x4 acc[4];
  #pragma unroll
  for (int n = 0; n < 4; n++) acc[n] = z4();
  #pragma unroll
  for (int kk = 0; kk < 4; kk++){
    float4 p = *(const float4*)(xr + kk*32);
    float4 q = *(const float4*)(xr + kk*32 + 4);
    h8 a = pack8(p, q);
    #pragma unroll
    for (int n = 0; n < 4; n++)
      acc[n] = __builtin_amdgcn_mfma_f32_16x16x32_f16(a, bf[n][kk], acc[n], 0, 0, 0);
  }
  #pragma unroll
  for (int n = 0; n < 4; n++){
    float bias = bt[16*n + lr];
    float a1 = 0.f, a2 = 0.f;
    #pragma unroll
    for (int r = 0; r < 4; r++){
      int g = node0 + 4*kb + r;
      float v = acc[n][r] + bias;
      if (g < NN){
        th[(size_t)g*NH + 16*n + lr] = f16b(v);
        a1 += v; a2 += v*v;
      }
    }
    a1 += __shfl_xor(a1, 16); a1 += __shfl_xor(a1, 32);
    a2 += __shfl_xor(a2, 16); a2 += __shfl_xor(a2, 32);
    if (kb == 0){
      sRed[w*NH + 16*n + lr] = a1;
      sRed[(4+w)*NH + 16*n + lr] = a2;
    }
  }
  __syncthreads();
  if (tid < NH){
    float a1 = sRed[tid] + sRed[NH+tid] + sRed[2*NH+tid] + sRed[3*NH+tid];
    float a2 = sRed[4*NH+tid] + sRed[5*NH+tid] + sRed[6*NH+tid] + sRed[7*NH+tid];
    unsafeAtomicAdd(&s1[tid], a1);
    unsafeAtomicAdd(&s2[tid], a2);
  }
}

// ---- MLP via MFMA: T = relu(relu(U@W1)@W2); V transposed through swizzled LDS
__global__ __launch_bounds__(256) void k_mlp_m(const u16* __restrict__ Uh, u16* __restrict__ Th,
    const u16* __restrict__ w1T, const u16* __restrict__ w2T, int wofs,
    float* __restrict__ s1, float* __restrict__ s2){
  __shared__ __align__(16) u16 sV[64*NH];
  __shared__ float sRed[8*NH];
  int tid = threadIdx.x;
  int w = tid >> 6, l = tid & 63;
  int lr = l & 15, kb = l >> 4;
  h8 b1[4][2], b2[4][2];
  #pragma unroll
  for (int n = 0; n < 4; n++)
    #pragma unroll
    for (int kk = 0; kk < 2; kk++){
      b1[n][kk] = *(const h8*)&w1T[wofs + (16*n + lr)*NH + kk*32 + kb*8];
      b2[n][kk] = *(const h8*)&w2T[wofs + (16*n + lr)*NH + kk*32 + kb*8];
    }
  int node0 = blockIdx.x*64;
  int rowA = node0 + 16*w + lr; if (rowA > NN-1) rowA = NN-1;
  f32x4 acc[4];
  #pragma unroll
  for (int n = 0; n < 4; n++) acc[n] = z4();
  #pragma unroll
  for (int kk = 0; kk < 2; kk++){
    h8 a = *(const h8*)&Uh[(size_t)rowA*NH + kk*32 + kb*8];
    #pragma unroll
    for (int n = 0; n < 4; n++)
      acc[n] = __builtin_amdgcn_mfma_f32_16x16x32_f16(a, b1[n][kk], acc[n], 0, 0, 0);
  }
  #pragma unroll
  for (int n = 0; n < 4; n++){
    #pragma unroll
    for (int r = 0; r < 4; r++){
      int row = 16*w + 4*kb + r;
      int col = 16*n + lr;
      sV[row*NH + (col ^ ((row & 7) << 3))] = f16b(fmaxf(acc[n][r], 0.f));
    }
  }
  __syncthreads();
  f32x4 acc2[4];
  #pragma unroll
  for (int n = 0; n < 4; n++) acc2[n] = z4();
  int rv = 16*w + lr;
  const u16* vrow = sV + rv*NH;
  #pragma unroll
  for (int kk = 0; kk < 2; kk++){
    h8 a = *(const h8*)&vrow[(kk*32 + kb*8) ^ ((rv & 7) << 3)];
    #pragma unroll
    for (int n = 0; n < 4; n++)
      acc2[n] = __builtin_amdgcn_mfma_f32_16x16x32_f16(a, b2[n][kk], acc2[n], 0, 0, 0);
  }
  #pragma unroll
  for (int n = 0; n < 4; n++){
    float a1 = 0.f, a2 = 0.f;
    #pragma unroll
    for (int r = 0; r < 4; r++){
      int g = node0 + 16*w + 4*kb + r;
      float v = fmaxf(acc2[n][r], 0.f);
      if (g < NN){
        Th[(size_t)g*NH + 16*n + lr] = f16b(v);
        a1 += v; a2 += v*v;
      }
    }
    a1 += __shfl_xor(a1, 16); a1 += __shfl_xor(a1, 32);
    a2 += __shfl_xor(a2, 16); a2 += __shfl_xor(a2, 32);
    if (kb == 0){
      sRed[w*NH + 16*n + lr] = a1;
      sRed[(4+w)*NH + 16*n + lr] = a2;
    }
  }
  __syncthreads();
  if (tid < NH){
    float a1 = sRed[tid] + sRed[NH+tid] + sRed[2*NH+tid] + sRed[3*NH+tid];
    float a2 = sRed[4*NH+tid] + sRed[5*NH+tid] + sRed[6*NH+tid] + sRed[7*NH+tid];
    unsafeAtomicAdd(&s1[tid], a1);
    unsafeAtomicAdd(&s2[tid], a2);
  }
}

// ---- per-graph embed with fused BN-fold (stats only; no h write)
__global__ __launch_bounds__(256) void k_embed(const u16* __restrict__ t,
    const float* __restrict__ s1, const float* __restrict__ s2,
    const void* __restrict__ gamma, const void* __restrict__ beta, int ofs,
    const int* __restrict__ starts, const int* __restrict__ flag,
    void* __restrict__ dout, int layer){
  __shared__ float sRed[8*NH];
  int g = blockIdx.x;
  int tx = threadIdx.x & 63, ty = threadIdx.x >> 6;
  int bf = flag[0];
  float gm = bf ? bf1(((const u16*)gamma)[ofs+tx]) : ((const float*)gamma)[ofs+tx];
  float be = bf ? bf1(((const u16*)beta)[ofs+tx])  : ((const float*)beta)[ofs+tx];
  float mean = s1[tx] * (1.f/NN);
  float var  = s2[tx] * (1.f/NN) - mean*mean;
  float rr = rsqrtf(fmaxf(var, 0.f) + 1e-5f);
  float sc = gm * rr;
  float sh = be - mean*sc;
  int st = starts[g], en = starts[g+1];
  float ls1 = 0.f, ls2 = 0.f;
  for (int n = st + ty; n < en; n += 4){
    float z = h1(t[(size_t)n*NH + tx]) * sc + sh;
    ls1 += z; ls2 += z*z;
  }
  sRed[ty*NH + tx] = ls1;
  sRed[(4+ty)*NH + tx] = ls2;
  __syncthreads();
  if (ty == 0){
    float a1 = sRed[tx] + sRed[NH+tx] + sRed[2*NH+tx] + sRed[3*NH+tx];
    float a2 = sRed[4*NH+tx] + sRed[5*NH+tx] + sRed[6*NH+tx] + sRed[7*NH+tx];
    int cnt = en - st;
    float inv = 1.f / (float)max(cnt, 1);
    float m = a1 * inv;
    float vv = a2 * inv - m*m;
    float s = sqrtf(fmaxf(vv, 0.f));
    size_t eidx = ((size_t)layer*NG + g)*NH + tx;
    size_t sidx = (size_t)4*NG*NH + eidx;
    if (bf){
      ((__hip_bfloat16*)dout)[eidx] = __float2bfloat16(m);
      ((__hip_bfloat16*)dout)[sidx] = __float2bfloat16(s);
    } else {
      ((float*)dout)[eidx] = m;
      ((float*)dout)[sidx] = s;
    }
  }
}

extern "C" void kernel_launch(void* const* d_in, const int* in_sizes, int n_in,
                              void* d_out, int out_size, void* d_ws, size_t ws_size,
                              hipStream_t stream) {
  const void* x    = d_in[0];
  const int* ei    = (const int*)d_in[1];
  const int* batch = (const int*)d_in[2];
  const void* Wt   = d_in[3];
  const void* bt   = d_in[4];
  const void* g0   = d_in[5];
  const void* b0   = d_in[6];
  const void* W1   = d_in[7];
  const void* W2   = d_in[8];
  const void* gs   = d_in[9];
  const void* bs   = d_in[10];

  u16*  uh16  = (u16*)d_ws;                       // NN*NH f16 (U)
  u16*  tb16  = uh16 + (size_t)NN*NH;             // NN*NH f16 (T)
  float* sAll = (float*)(tb16 + (size_t)NN*NH);   // 4 stages x (s1[64], s2[64]) — zeroed
  int* bcount = (int*)(sAll + 512);               // 256 — zeroed (contiguous with sAll)
  int* bstart = bcount + NB;                      // 257 (pad to 288)
  int* bcur   = bstart + 288;                     // 256
  int* starts = bcur + NB;                        // 512
  int* flag   = starts + 512;                     // 64
  int* rowptr = flag + 64;                        // NN+64
  u32* pkE    = (u32*)(rowptr + NN + 64);         // NE packed (dst<<16|src)
  int* csr    = (int*)(pkE + NE);                 // NE
  u16* wtT    = (u16*)(csr + NE);                 // NH*NF f16
  u16* w1T    = wtT + (size_t)NH*NF;              // 3*NH*NH f16
  u16* w2T    = w1T + (size_t)3*NH*NH;            // 3*NH*NH f16

  hipMemsetAsync(sAll, 0, 512*sizeof(float) + NB*sizeof(int), stream);  // sAll + bcount
  k_detect<<<1, 64, 0, stream>>>((const u32*)x, flag);
  k_bounds<<<1, 512, 0, stream>>>(batch, starts);
  k_prep<<<48, 256, 0, stream>>>((const float*)Wt, (const float*)W1, (const float*)W2, wtT, w1T, w2T);

  k_bhist<<<NBLK, 256, 0, stream>>>(ei, bcount);
  k_bscan<<<1, 256, 0, stream>>>(bcount, bstart, bcur);
  k_bscat<<<NBLK, 256, 0, stream>>>(ei, bcur, pkE);
  k_bfill<<<NB, 256, 0, stream>>>(pkE, bstart, rowptr, csr);

  k_transform_m<<<(NN+63)/64, 256, 0, stream>>>((const float*)x, wtT, (const float*)bt, tb16, sAll, sAll + 64);
  k_embed<<<NG, 256, 0, stream>>>(tb16, sAll, sAll + 64, g0, b0, 0, starts, flag, d_out, 0);

  for (int l = 0; l < 3; l++){
    float* sIn  = sAll + (size_t)l*128;
    float* sOut = sAll + (size_t)(l+1)*128;
    const void* gg = (l == 0) ? g0 : gs;
    const void* bb = (l == 0) ? b0 : bs;
    int ofs = (l == 0) ? 0 : (l-1)*NH;
    k_gather<<<(NN+3)/4, 256, 0, stream>>>(tb16, rowptr, csr, uh16, sIn, sIn + 64, gg, bb, ofs, flag);
    k_mlp_m<<<(NN+63)/64, 256, 0, stream>>>(uh16, tb16, w1T, w2T, l*NH*NH, sOut, sOut + 64);
    k_embed<<<NG, 256, 0, stream>>>(tb16, sOut, sOut + 64, gs, bs, l*NH, starts, flag, d_out, l+1);
  }
}

// Round 3
// 366.286 us; speedup vs baseline: 1.1974x; 1.0010x over previous
//
#include <hip/hip_runtime.h>
#include <hip/hip_bf16.h>

#define NN 50000
#define NE 800000
#define NG 500
#define NF 128
#define NH 64
#define NB 256            // node buckets
#define NPB 196           // nodes per bucket: 256*196 = 50176 >= NN
#define EPB 4096          // edges per block (hist/scatter)
#define NBLK ((NE + EPB - 1)/EPB)   // 196

typedef unsigned int u32;
typedef unsigned short u16;
typedef _Float16 h2 __attribute__((ext_vector_type(2)));
typedef _Float16 h8 __attribute__((ext_vector_type(8)));   // MFMA A/B frag (4 VGPR)
typedef float f32x4 __attribute__((ext_vector_type(4)));   // MFMA acc

__device__ __forceinline__ float bf1(u16 v){ return __uint_as_float(((u32)v) << 16); }
__device__ __forceinline__ float h1(u16 v){ return (float)__builtin_bit_cast(_Float16, v); }
__device__ __forceinline__ u32 pk(float a, float b){
  return __builtin_bit_cast(u32, __builtin_amdgcn_cvt_pkrtz(a, b));
}
__device__ __forceinline__ h2 uph(u32 u){ return __builtin_bit_cast(h2, u); }
__device__ __forceinline__ u16 f16b(float f){ return __builtin_bit_cast(u16, (_Float16)f); }

// decode 8 f16 -> 8 f32
__device__ __forceinline__ void cv8h(uint4 q, float* f){
  h2 v0 = uph(q.x), v1 = uph(q.y), v2 = uph(q.z), v3 = uph(q.w);
  f[0]=(float)v0.x; f[1]=(float)v0.y; f[2]=(float)v1.x; f[3]=(float)v1.y;
  f[4]=(float)v2.x; f[5]=(float)v2.y; f[6]=(float)v3.x; f[7]=(float)v3.y;
}

__device__ __forceinline__ h8 pack8(float4 p, float4 q){
  uint4 t;
  t.x = pk(p.x, p.y); t.y = pk(p.z, p.w);
  t.z = pk(q.x, q.y); t.w = pk(q.z, q.w);
  return __builtin_bit_cast(h8, t);
}
__device__ __forceinline__ f32x4 z4(){
  f32x4 v; v[0]=0.f; v[1]=0.f; v[2]=0.f; v[3]=0.f; return v;
}

// ---- fused init: prep (blocks 0..47), detect+bounds (block 48)
__global__ __launch_bounds__(256) void k_init(const u32* __restrict__ xw, int* __restrict__ flag,
    const int* __restrict__ batch, int* __restrict__ starts,
    const float* __restrict__ Wt, const float* __restrict__ W1, const float* __restrict__ W2,
    u16* __restrict__ wtT, u16* __restrict__ w1T, u16* __restrict__ w2T){
  int b = blockIdx.x, tid = threadIdx.x;
  if (b < 48){
    int t = b*256 + tid;
    if (t < NH*NF){                       // wtT[c][k] = Wt[k][c]
      int c = t >> 7, k = t & 127;
      wtT[t] = f16b(Wt[(size_t)k*NH + c]);
    }
    if (t < 3*NH*NH){                     // w{1,2}T[l][c][k] = W{1,2}[l][k][c]
      int l = t >> 12, c = (t >> 6) & 63, k = t & 63;
      w1T[t] = f16b(W1[(size_t)l*NH*NH + k*NH + c]);
      w2T[t] = f16b(W2[(size_t)l*NH*NH + k*NH + c]);
    }
  } else {
    if (tid < 64){                        // dtype probe (wave 0 only)
      u32 w = xw[tid];
      u32 lo = w & 0xFFFFu;
      u32 e = (lo >> 7) & 0xFFu;
      bool vote = (e >= 0x60u && e <= 0x8Fu);
      unsigned long long m = __ballot(vote);
      if (tid == 0) flag[0] = (__popcll(m) >= 32) ? 1 : 0;
    }
    for (int g = tid; g <= NG; g += 256){ // graph boundaries
      int lo = 0, hi = NN;
      while (lo < hi){ int mid = (lo + hi) >> 1; if (batch[mid] < g) lo = mid + 1; else hi = mid; }
      starts[g] = lo;
    }
  }
}

// ==== bucketed CSR build ====

// phase 1+2: per-bucket edge counts; last block scans -> bstart/bcur
__global__ __launch_bounds__(256) void k_bhist(const int* __restrict__ ei, int* __restrict__ bcount,
    int* __restrict__ bstart, int* __restrict__ bcur, int* __restrict__ ticket){
  __shared__ int h[NB];
  __shared__ int part[NB];
  __shared__ int isLast;
  int tid = threadIdx.x;
  h[tid] = 0;
  __syncthreads();
  int e0 = blockIdx.x*EPB;
  #pragma unroll
  for (int i = 0; i < 16; i++){
    int e = e0 + i*256 + tid;
    if (e < NE) atomicAdd(&h[ei[NE + e] / NPB], 1);
  }
  __syncthreads();
  if (h[tid]) atomicAdd(&bcount[tid], h[tid]);
  __threadfence();
  if (tid == 0) isLast = (atomicAdd(ticket, 1) == (int)gridDim.x - 1);
  __syncthreads();
  if (!isLast) return;
  int v = atomicAdd(&bcount[tid], 0);     // coherent read
  part[tid] = v;
  __syncthreads();
  for (int off = 1; off < 256; off <<= 1){
    int u = (tid >= off) ? part[tid-off] : 0;
    __syncthreads();
    part[tid] += u;
    __syncthreads();
  }
  int ex = part[tid] - v;
  bstart[tid] = ex;
  bcur[tid] = ex;
  if (tid == 0) bstart[NB] = NE;
}

// phase 3: LDS bucket-sort then near-coalesced scatter of packed edges (dst<<16|src)
__global__ __launch_bounds__(256) void k_bscat(const int* __restrict__ ei,
    int* __restrict__ bcur, u32* __restrict__ pkE){
  __shared__ int h[NB];
  __shared__ int loff[NB];
  __shared__ int base[NB];
  __shared__ int part[NB];
  __shared__ u32 sv[EPB];     // 16 KB
  int tid = threadIdx.x;
  h[tid] = 0;
  __syncthreads();
  int e0 = blockIdx.x*EPB;
  u32 meta[16], vals[16];
  #pragma unroll
  for (int i = 0; i < 16; i++){
    int e = e0 + i*256 + tid;
    if (e < NE){
      int s = ei[e], d = ei[NE + e];
      int b = d / NPB;
      int r = atomicAdd(&h[b], 1);        // rank within block's bucket group
      meta[i] = ((u32)b << 16) | (u32)r;
      vals[i] = ((u32)d << 16) | (u32)s;
    } else meta[i] = 0xFFFFFFFFu;
  }
  __syncthreads();
  int cnt = h[tid];
  part[tid] = cnt;
  __syncthreads();
  for (int off = 1; off < 256; off <<= 1){
    int u = (tid >= off) ? part[tid-off] : 0;
    __syncthreads();
    part[tid] += u;
    __syncthreads();
  }
  loff[tid] = part[tid] - cnt;
  base[tid] = cnt ? atomicAdd(&bcur[tid], cnt) : 0;   // one atomic per (block,bucket)
  __syncthreads();
  #pragma unroll
  for (int i = 0; i < 16; i++){
    if (meta[i] != 0xFFFFFFFFu){
      int b = meta[i] >> 16, r = meta[i] & 0xFFFFu;
      sv[loff[b] + r] = vals[i];
    }
  }
  __syncthreads();
  int total = min(EPB, NE - e0);
  for (int j = tid; j < total; j += 256){   // bucket-sorted -> runs are contiguous
    u32 v = sv[j];
    int b = (int)(v >> 16) / NPB;
    pkE[base[b] + (j - loff[b])] = v;
  }
}

// phase 4: per-bucket local CSR: LDS node-histogram + scan -> rowptr + dense csr
__global__ __launch_bounds__(256) void k_bfill(const u32* __restrict__ pkE,
    const int* __restrict__ bstart, int* __restrict__ rowptr, int* __restrict__ csr){
  __shared__ int part[NB];
  __shared__ int cur[NB];
  int b = blockIdx.x;
  int tid = threadIdx.x;
  int nb0 = b*NPB;
  int nr = min(NPB, NN - nb0);
  int rbeg = bstart[b], rend = bstart[b+1];
  part[tid] = 0;
  __syncthreads();
  for (int j = rbeg + tid; j < rend; j += 256){
    u32 pe = pkE[j];
    atomicAdd(&part[(int)(pe >> 16) - nb0], 1);
  }
  __syncthreads();
  int v = part[tid];
  __syncthreads();
  for (int off = 1; off < 256; off <<= 1){
    int u = (tid >= off) ? part[tid-off] : 0;
    __syncthreads();
    part[tid] += u;
    __syncthreads();
  }
  int ex = part[tid] - v;
  if (tid < nr) rowptr[nb0 + tid] = rbeg + ex;
  if (b == NB-1 && tid == 0) rowptr[NN] = NE;
  cur[tid] = ex;
  __syncthreads();
  for (int j = rbeg + tid; j < rend; j += 256){
    u32 pe = pkE[j];
    int node = (int)(pe >> 16) - nb0;
    int p = atomicAdd(&cur[node], 1);
    csr[rbeg + p] = (int)(pe & 0xFFFFu);
  }
}

// ---- transform via MFMA: T = x @ Wt + bt, f16 out, col-sums to s1/s2
__global__ __launch_bounds__(256) void k_transform_m(const float* __restrict__ x,
    const u16* __restrict__ wtT, const float* __restrict__ bt,
    u16* __restrict__ th, float* __restrict__ s1){
  __shared__ float sRed[8*NH];
  int tid = threadIdx.x;
  int w = tid >> 6, l = tid & 63;
  int lr = l & 15, kb = l >> 4;
  h8 bf[4][4];
  #pragma unroll
  for (int n = 0; n < 4; n++)
    #pragma unroll
    for (int kk = 0; kk < 4; kk++)
      bf[n][kk] = *(const h8*)&wtT[(size_t)(16*n + lr)*NF + kk*32 + kb*8];
  int node0 = blockIdx.x*64 + w*16;
  int rowA = node0 + lr; if (rowA > NN-1) rowA = NN-1;
  const float* xr = x + (size_t)rowA*NF + kb*8;
  f32x4 acc[4];
  #pragma unroll
  for (int n = 0; n < 4; n++) acc[n] = z4();
  #pragma unroll
  for (int kk = 0; kk < 4; kk++){
    float4 p = *(const float4*)(xr + kk*32);
    float4 q = *(const float4*)(xr + kk*32 + 4);
    h8 a = pack8(p, q);
    #pragma unroll
    for (int n = 0; n < 4; n++)
      acc[n] = __builtin_amdgcn_mfma_f32_16x16x32_f16(a, bf[n][kk], acc[n], 0, 0, 0);
  }
  #pragma unroll
  for (int n = 0; n < 4; n++){
    float bias = bt[16*n + lr];
    float a1 = 0.f, a2 = 0.f;
    #pragma unroll
    for (int r = 0; r < 4; r++){
      int g = node0 + 4*kb + r;
      float v = acc[n][r] + bias;
      if (g < NN){
        th[(size_t)g*NH + 16*n + lr] = f16b(v);
        a1 += v; a2 += v*v;
      }
    }
    a1 += __shfl_xor(a1, 16); a1 += __shfl_xor(a1, 32);
    a2 += __shfl_xor(a2, 16); a2 += __shfl_xor(a2, 32);
    if (kb == 0){
      sRed[w*NH + 16*n + lr] = a1;
      sRed[(4+w)*NH + 16*n + lr] = a2;
    }
  }
  __syncthreads();
  if (tid < NH){
    float a1 = sRed[tid] + sRed[NH+tid] + sRed[2*NH+tid] + sRed[3*NH+tid];
    float a2 = sRed[4*NH+tid] + sRed[5*NH+tid] + sRed[6*NH+tid] + sRed[7*NH+tid];
    unsafeAtomicAdd(&s1[tid], a1);
    unsafeAtomicAdd(&s1[NH+tid], a2);
  }
}

// ---- fused gather + MLP: U (BN-affine aggregated) -> swizzled LDS -> MFMA MLP
// reads t (stage l), writes Th (stage l+1, DIFFERENT buffer), stats to s1o
__global__ __launch_bounds__(256) void k_gmlp(const u16* __restrict__ t,
    const int* __restrict__ rowptr, const int* __restrict__ csr, u16* __restrict__ Th,
    const u16* __restrict__ w1T, const u16* __restrict__ w2T, int wofs,
    const float* __restrict__ s1i,
    const void* __restrict__ gamma, const void* __restrict__ beta, int ofs,
    const int* __restrict__ flag, float* __restrict__ s1o){
  __shared__ __align__(16) u16 sU[64*NH];   // 8 KB, XOR-swizzled
  __shared__ __align__(16) u16 sV[64*NH];   // 8 KB, XOR-swizzled
  __shared__ float sRed[8*NH];
  __shared__ float scs[NH], shs[NH];
  int tid = threadIdx.x;
  if (tid < NH){
    int bfl = flag[0];
    float gm = bfl ? bf1(((const u16*)gamma)[ofs+tid]) : ((const float*)gamma)[ofs+tid];
    float be = bfl ? bf1(((const u16*)beta)[ofs+tid])  : ((const float*)beta)[ofs+tid];
    float mean = s1i[tid] * (1.f/NN);
    float var  = s1i[NH+tid] * (1.f/NN) - mean*mean;
    float rr = rsqrtf(fmaxf(var, 0.f) + 1e-5f);
    float sc = gm * rr;
    scs[tid] = sc;
    shs[tid] = be - mean*sc;
  }
  __syncthreads();
  int w = tid >> 6, lane = tid & 63;
  int chunk = lane & 7, epar = lane >> 3;
  int node0 = blockIdx.x*64;
  // ---- gather phase: wave w fills LDS rows w*16 .. w*16+15
  for (int idx = 0; idx < 16; idx++){
    int nl = w*16 + idx;
    int node = node0 + nl;
    int swz = (nl & 7) << 3;
    if (node < NN){
      int beg = rowptr[node], en = rowptr[node+1];
      float acc[8] = {0.f,0.f,0.f,0.f,0.f,0.f,0.f,0.f};
      if (epar == 0){
        uint4 q = *(const uint4*)&t[(size_t)node*NH + chunk*8];
        cv8h(q, acc);
      }
      int j = beg + epar;
      for (; j + 8 < en; j += 16){
        int src0 = csr[j];
        int src1 = csr[j+8];
        uint4 q0 = *(const uint4*)&t[(size_t)src0*NH + chunk*8];
        uint4 q1 = *(const uint4*)&t[(size_t)src1*NH + chunk*8];
        float f0[8], f1[8];
        cv8h(q0, f0);
        cv8h(q1, f1);
        #pragma unroll
        for (int i = 0; i < 8; i++) acc[i] += f0[i] + f1[i];
      }
      if (j < en){
        int src = csr[j];
        uint4 q = *(const uint4*)&t[(size_t)src*NH + chunk*8];
        float f[8]; cv8h(q, f);
        #pragma unroll
        for (int i = 0; i < 8; i++) acc[i] += f[i];
      }
      #pragma unroll
      for (int i = 0; i < 8; i++){
        acc[i] += __shfl_xor(acc[i], 8);
        acc[i] += __shfl_xor(acc[i], 16);
        acc[i] += __shfl_xor(acc[i], 32);
      }
      if (epar == 0){
        float deg1 = (float)(en - beg + 1);
        float o[8];
        #pragma unroll
        for (int i = 0; i < 8; i++)
          o[i] = scs[chunk*8+i]*acc[i] + deg1*shs[chunk*8+i];
        uint4 ov;
        ov.x = pk(o[0], o[1]); ov.y = pk(o[2], o[3]);
        ov.z = pk(o[4], o[5]); ov.w = pk(o[6], o[7]);
        *(uint4*)&sU[nl*NH + ((chunk*8) ^ swz)] = ov;
      }
    } else if (epar == 0){
      uint4 zz; zz.x = 0; zz.y = 0; zz.z = 0; zz.w = 0;
      *(uint4*)&sU[nl*NH + ((chunk*8) ^ swz)] = zz;
    }
  }
  __syncthreads();
  // ---- MLP phase
  int lr = lane & 15, kb = lane >> 4;
  h8 b1[4][2], b2[4][2];
  #pragma unroll
  for (int n = 0; n < 4; n++)
    #pragma unroll
    for (int kk = 0; kk < 2; kk++){
      b1[n][kk] = *(const h8*)&w1T[wofs + (16*n + lr)*NH + kk*32 + kb*8];
      b2[n][kk] = *(const h8*)&w2T[wofs + (16*n + lr)*NH + kk*32 + kb*8];
    }
  int rv = 16*w + lr;
  f32x4 acc[4];
  #pragma unroll
  for (int n = 0; n < 4; n++) acc[n] = z4();
  const u16* urow = sU + rv*NH;
  #pragma unroll
  for (int kk = 0; kk < 2; kk++){
    h8 a = *(const h8*)&urow[(kk*32 + kb*8) ^ ((rv & 7) << 3)];
    #pragma unroll
    for (int n = 0; n < 4; n++)
      acc[n] = __builtin_amdgcn_mfma_f32_16x16x32_f16(a, b1[n][kk], acc[n], 0, 0, 0);
  }
  #pragma unroll
  for (int n = 0; n < 4; n++){
    #pragma unroll
    for (int r = 0; r < 4; r++){
      int row = 16*w + 4*kb + r;
      int col = 16*n + lr;
      sV[row*NH + (col ^ ((row & 7) << 3))] = f16b(fmaxf(acc[n][r], 0.f));
    }
  }
  __syncthreads();
  f32x4 acc2[4];
  #pragma unroll
  for (int n = 0; n < 4; n++) acc2[n] = z4();
  const u16* vrow = sV + rv*NH;
  #pragma unroll
  for (int kk = 0; kk < 2; kk++){
    h8 a = *(const h8*)&vrow[(kk*32 + kb*8) ^ ((rv & 7) << 3)];
    #pragma unroll
    for (int n = 0; n < 4; n++)
      acc2[n] = __builtin_amdgcn_mfma_f32_16x16x32_f16(a, b2[n][kk], acc2[n], 0, 0, 0);
  }
  #pragma unroll
  for (int n = 0; n < 4; n++){
    float a1 = 0.f, a2 = 0.f;
    #pragma unroll
    for (int r = 0; r < 4; r++){
      int g = node0 + 16*w + 4*kb + r;
      float v = fmaxf(acc2[n][r], 0.f);
      if (g < NN){
        Th[(size_t)g*NH + 16*n + lr] = f16b(v);
        a1 += v; a2 += v*v;
      }
    }
    a1 += __shfl_xor(a1, 16); a1 += __shfl_xor(a1, 32);
    a2 += __shfl_xor(a2, 16); a2 += __shfl_xor(a2, 32);
    if (kb == 0){
      sRed[w*NH + 16*n + lr] = a1;
      sRed[(4+w)*NH + 16*n + lr] = a2;
    }
  }
  __syncthreads();
  if (tid < NH){
    float a1 = sRed[tid] + sRed[NH+tid] + sRed[2*NH+tid] + sRed[3*NH+tid];
    float a2 = sRed[4*NH+tid] + sRed[5*NH+tid] + sRed[6*NH+tid] + sRed[7*NH+tid];
    unsafeAtomicAdd(&s1o[tid], a1);
    unsafeAtomicAdd(&s1o[NH+tid], a2);
  }
}

// ---- per-graph embed with fused BN-fold (stats only); 512 threads for latency hiding
__global__ __launch_bounds__(512) void k_embed(const u16* __restrict__ t,
    const float* __restrict__ s1,
    const void* __restrict__ gamma, const void* __restrict__ beta, int ofs,
    const int* __restrict__ starts, const int* __restrict__ flag,
    void* __restrict__ dout, int layer){
  __shared__ float sRed[16*NH];
  int g = blockIdx.x;
  int tx = threadIdx.x & 63, ty = threadIdx.x >> 6;   // ty 0..7
  int bf = flag[0];
  float gm = bf ? bf1(((const u16*)gamma)[ofs+tx]) : ((const float*)gamma)[ofs+tx];
  float be = bf ? bf1(((const u16*)beta)[ofs+tx])  : ((const float*)beta)[ofs+tx];
  float mean = s1[tx] * (1.f/NN);
  float var  = s1[NH+tx] * (1.f/NN) - mean*mean;
  float rr = rsqrtf(fmaxf(var, 0.f) + 1e-5f);
  float sc = gm * rr;
  float sh = be - mean*sc;
  int st = starts[g], en = starts[g+1];
  float ls1 = 0.f, ls2 = 0.f;
  for (int n = st + ty; n < en; n += 8){
    float z = h1(t[(size_t)n*NH + tx]) * sc + sh;
    ls1 += z; ls2 += z*z;
  }
  sRed[ty*NH + tx] = ls1;
  sRed[(8+ty)*NH + tx] = ls2;
  __syncthreads();
  if (ty == 0){
    float a1 = 0.f, a2 = 0.f;
    #pragma unroll
    for (int r = 0; r < 8; r++){
      a1 += sRed[r*NH + tx];
      a2 += sRed[(8+r)*NH + tx];
    }
    int cnt = en - st;
    float inv = 1.f / (float)max(cnt, 1);
    float m = a1 * inv;
    float vv = a2 * inv - m*m;
    float s = sqrtf(fmaxf(vv, 0.f));
    size_t eidx = ((size_t)layer*NG + g)*NH + tx;
    size_t sidx = (size_t)4*NG*NH + eidx;
    if (bf){
      ((__hip_bfloat16*)dout)[eidx] = __float2bfloat16(m);
      ((__hip_bfloat16*)dout)[sidx] = __float2bfloat16(s);
    } else {
      ((float*)dout)[eidx] = m;
      ((float*)dout)[sidx] = s;
    }
  }
}

extern "C" void kernel_launch(void* const* d_in, const int* in_sizes, int n_in,
                              void* d_out, int out_size, void* d_ws, size_t ws_size,
                              hipStream_t stream) {
  const void* x    = d_in[0];
  const int* ei    = (const int*)d_in[1];
  const int* batch = (const int*)d_in[2];
  const void* Wt   = d_in[3];
  const void* bt   = d_in[4];
  const void* g0   = d_in[5];
  const void* b0   = d_in[6];
  const void* W1   = d_in[7];
  const void* W2   = d_in[8];
  const void* gs   = d_in[9];
  const void* bs   = d_in[10];

  u16*  tA    = (u16*)d_ws;                       // NN*NH f16 (double-buffered t)
  u16*  tB    = tA + (size_t)NN*NH;               // NN*NH f16
  float* sAll = (float*)(tB + (size_t)NN*NH);     // 4 stages x (s1[64], s2[64]) — zeroed
  int* bcount = (int*)(sAll + 512);               // 256 — zeroed
  int* ticket = bcount + NB;                      // 64 (pad) — zeroed
  int* bstart = ticket + 64;                      // 257 (pad to 288)
  int* bcur   = bstart + 288;                     // 256
  int* starts = bcur + NB;                        // 512
  int* flag   = starts + 512;                     // 64
  int* rowptr = flag + 64;                        // NN+64
  u32* pkE    = (u32*)(rowptr + NN + 64);         // NE packed (dst<<16|src)
  int* csr    = (int*)(pkE + NE);                 // NE
  u16* wtT    = (u16*)(csr + NE);                 // NH*NF f16 (16B-aligned)
  u16* w1T    = wtT + (size_t)NH*NF;              // 3*NH*NH f16
  u16* w2T    = w1T + (size_t)3*NH*NH;            // 3*NH*NH f16

  hipMemsetAsync(sAll, 0, (512 + NB + 64)*sizeof(float), stream);   // sAll + bcount + ticket
  k_init<<<49, 256, 0, stream>>>((const u32*)x, flag, batch, starts,
      (const float*)Wt, (const float*)W1, (const float*)W2, wtT, w1T, w2T);
  k_bhist<<<NBLK, 256, 0, stream>>>(ei, bcount, bstart, bcur, ticket);
  k_bscat<<<NBLK, 256, 0, stream>>>(ei, bcur, pkE);
  k_bfill<<<NB, 256, 0, stream>>>(pkE, bstart, rowptr, csr);

  k_transform_m<<<(NN+63)/64, 256, 0, stream>>>((const float*)x, wtT, (const float*)bt, tA, sAll);
  k_embed<<<NG, 512, 0, stream>>>(tA, sAll, g0, b0, 0, starts, flag, d_out, 0);

  u16* tin = tA;
  u16* tout = tB;
  for (int l = 0; l < 3; l++){
    float* sIn  = sAll + (size_t)l*128;
    float* sOut = sAll + (size_t)(l+1)*128;
    const void* gg = (l == 0) ? g0 : gs;
    const void* bb = (l == 0) ? b0 : bs;
    int ofs = (l == 0) ? 0 : (l-1)*NH;
    k_gmlp<<<(NN+63)/64, 256, 0, stream>>>(tin, rowptr, csr, tout, w1T, w2T, l*NH*NH,
        sIn, gg, bb, ofs, flag, sOut);
    k_embed<<<NG, 512, 0, stream>>>(tout, sOut, gs, bs, l*NH, starts, flag, d_out, l+1);
    u16* tmp = tin; tin = tout; tout = tmp;
  }
}

// Round 4
// 332.905 us; speedup vs baseline: 1.3175x; 1.1003x over previous
//
#include <hip/hip_runtime.h>
#include <hip/hip_bf16.h>

#define NN 50000
#define NE 800000
#define NG 500
#define NF 128
#define NH 64
#define NB 256            // node buckets
#define NPB 196           // nodes per bucket: 256*196 = 50176 >= NN
#define EPB 4096          // edges per block (hist/scatter)
#define NBLK ((NE + EPB - 1)/EPB)   // 196
#define CSR_LDS 2048      // per-block LDS csr slice cap

typedef unsigned int u32;
typedef unsigned short u16;
typedef _Float16 h2 __attribute__((ext_vector_type(2)));
typedef _Float16 h8 __attribute__((ext_vector_type(8)));   // MFMA A/B frag (4 VGPR)
typedef float f32x4 __attribute__((ext_vector_type(4)));   // MFMA acc

__device__ __forceinline__ float bf1(u16 v){ return __uint_as_float(((u32)v) << 16); }
__device__ __forceinline__ float h1(u16 v){ return (float)__builtin_bit_cast(_Float16, v); }
__device__ __forceinline__ u32 pk(float a, float b){
  return __builtin_bit_cast(u32, __builtin_amdgcn_cvt_pkrtz(a, b));
}
__device__ __forceinline__ h2 uph(u32 u){ return __builtin_bit_cast(h2, u); }
__device__ __forceinline__ u16 f16b(float f){ return __builtin_bit_cast(u16, (_Float16)f); }

// decode 8 f16 -> 8 f32
__device__ __forceinline__ void cv8h(uint4 q, float* f){
  h2 v0 = uph(q.x), v1 = uph(q.y), v2 = uph(q.z), v3 = uph(q.w);
  f[0]=(float)v0.x; f[1]=(float)v0.y; f[2]=(float)v1.x; f[3]=(float)v1.y;
  f[4]=(float)v2.x; f[5]=(float)v2.y; f[6]=(float)v3.x; f[7]=(float)v3.y;
}

__device__ __forceinline__ h8 pack8(float4 p, float4 q){
  uint4 t;
  t.x = pk(p.x, p.y); t.y = pk(p.z, p.w);
  t.z = pk(q.x, q.y); t.w = pk(q.z, q.w);
  return __builtin_bit_cast(h8, t);
}
__device__ __forceinline__ f32x4 z4(){
  f32x4 v; v[0]=0.f; v[1]=0.f; v[2]=0.f; v[3]=0.f; return v;
}

// ---- fused init: prep (blocks 0..47), detect+bounds (block 48)
__global__ __launch_bounds__(256) void k_init(const u32* __restrict__ xw, int* __restrict__ flag,
    const int* __restrict__ batch, int* __restrict__ starts,
    const float* __restrict__ Wt, const float* __restrict__ W1, const float* __restrict__ W2,
    u16* __restrict__ wtT, u16* __restrict__ w1T, u16* __restrict__ w2T){
  int b = blockIdx.x, tid = threadIdx.x;
  if (b < 48){
    int t = b*256 + tid;
    if (t < NH*NF){                       // wtT[c][k] = Wt[k][c]
      int c = t >> 7, k = t & 127;
      wtT[t] = f16b(Wt[(size_t)k*NH + c]);
    }
    if (t < 3*NH*NH){                     // w{1,2}T[l][c][k] = W{1,2}[l][k][c]
      int l = t >> 12, c = (t >> 6) & 63, k = t & 63;
      w1T[t] = f16b(W1[(size_t)l*NH*NH + k*NH + c]);
      w2T[t] = f16b(W2[(size_t)l*NH*NH + k*NH + c]);
    }
  } else {
    if (tid < 64){                        // dtype probe (wave 0 only)
      u32 w = xw[tid];
      u32 lo = w & 0xFFFFu;
      u32 e = (lo >> 7) & 0xFFu;
      bool vote = (e >= 0x60u && e <= 0x8Fu);
      unsigned long long m = __ballot(vote);
      if (tid == 0) flag[0] = (__popcll(m) >= 32) ? 1 : 0;
    }
    for (int g = tid; g <= NG; g += 256){ // graph boundaries
      int lo = 0, hi = NN;
      while (lo < hi){ int mid = (lo + hi) >> 1; if (batch[mid] < g) lo = mid + 1; else hi = mid; }
      starts[g] = lo;
    }
  }
}

// ==== bucketed CSR build ====

// phase 1+2: per-bucket edge counts; last block scans -> bstart/bcur
__global__ __launch_bounds__(256) void k_bhist(const int* __restrict__ ei, int* __restrict__ bcount,
    int* __restrict__ bstart, int* __restrict__ bcur, int* __restrict__ ticket){
  __shared__ int h[NB];
  __shared__ int part[NB];
  __shared__ int isLast;
  int tid = threadIdx.x;
  h[tid] = 0;
  __syncthreads();
  int e0 = blockIdx.x*EPB;
  #pragma unroll
  for (int i = 0; i < 16; i++){
    int e = e0 + i*256 + tid;
    if (e < NE) atomicAdd(&h[ei[NE + e] / NPB], 1);
  }
  __syncthreads();
  if (h[tid]) atomicAdd(&bcount[tid], h[tid]);
  __threadfence();
  if (tid == 0) isLast = (atomicAdd(ticket, 1) == (int)gridDim.x - 1);
  __syncthreads();
  if (!isLast) return;
  int v = atomicAdd(&bcount[tid], 0);     // coherent read
  part[tid] = v;
  __syncthreads();
  for (int off = 1; off < 256; off <<= 1){
    int u = (tid >= off) ? part[tid-off] : 0;
    __syncthreads();
    part[tid] += u;
    __syncthreads();
  }
  int ex = part[tid] - v;
  bstart[tid] = ex;
  bcur[tid] = ex;
  if (tid == 0) bstart[NB] = NE;
}

// phase 3: LDS bucket-sort then near-coalesced scatter of packed edges (dst<<16|src)
__global__ __launch_bounds__(256) void k_bscat(const int* __restrict__ ei,
    int* __restrict__ bcur, u32* __restrict__ pkE){
  __shared__ int h[NB];
  __shared__ int loff[NB];
  __shared__ int base[NB];
  __shared__ int part[NB];
  __shared__ u32 sv[EPB];     // 16 KB
  int tid = threadIdx.x;
  h[tid] = 0;
  __syncthreads();
  int e0 = blockIdx.x*EPB;
  u32 meta[16], vals[16];
  #pragma unroll
  for (int i = 0; i < 16; i++){
    int e = e0 + i*256 + tid;
    if (e < NE){
      int s = ei[e], d = ei[NE + e];
      int b = d / NPB;
      int r = atomicAdd(&h[b], 1);        // rank within block's bucket group
      meta[i] = ((u32)b << 16) | (u32)r;
      vals[i] = ((u32)d << 16) | (u32)s;
    } else meta[i] = 0xFFFFFFFFu;
  }
  __syncthreads();
  int cnt = h[tid];
  part[tid] = cnt;
  __syncthreads();
  for (int off = 1; off < 256; off <<= 1){
    int u = (tid >= off) ? part[tid-off] : 0;
    __syncthreads();
    part[tid] += u;
    __syncthreads();
  }
  loff[tid] = part[tid] - cnt;
  base[tid] = cnt ? atomicAdd(&bcur[tid], cnt) : 0;   // one atomic per (block,bucket)
  __syncthreads();
  #pragma unroll
  for (int i = 0; i < 16; i++){
    if (meta[i] != 0xFFFFFFFFu){
      int b = meta[i] >> 16, r = meta[i] & 0xFFFFu;
      sv[loff[b] + r] = vals[i];
    }
  }
  __syncthreads();
  int total = min(EPB, NE - e0);
  for (int j = tid; j < total; j += 256){   // bucket-sorted -> runs are contiguous
    u32 v = sv[j];
    int b = (int)(v >> 16) / NPB;
    pkE[base[b] + (j - loff[b])] = v;
  }
}

// phase 4: per-bucket local CSR: LDS node-histogram + scan -> rowptr + dense csr
__global__ __launch_bounds__(256) void k_bfill(const u32* __restrict__ pkE,
    const int* __restrict__ bstart, int* __restrict__ rowptr, int* __restrict__ csr){
  __shared__ int part[NB];
  __shared__ int cur[NB];
  int b = blockIdx.x;
  int tid = threadIdx.x;
  int nb0 = b*NPB;
  int nr = min(NPB, NN - nb0);
  int rbeg = bstart[b], rend = bstart[b+1];
  part[tid] = 0;
  __syncthreads();
  for (int j = rbeg + tid; j < rend; j += 256){
    u32 pe = pkE[j];
    atomicAdd(&part[(int)(pe >> 16) - nb0], 1);
  }
  __syncthreads();
  int v = part[tid];
  __syncthreads();
  for (int off = 1; off < 256; off <<= 1){
    int u = (tid >= off) ? part[tid-off] : 0;
    __syncthreads();
    part[tid] += u;
    __syncthreads();
  }
  int ex = part[tid] - v;
  if (tid < nr) rowptr[nb0 + tid] = rbeg + ex;
  if (b == NB-1 && tid == 0) rowptr[NN] = NE;
  cur[tid] = ex;
  __syncthreads();
  for (int j = rbeg + tid; j < rend; j += 256){
    u32 pe = pkE[j];
    int node = (int)(pe >> 16) - nb0;
    int p = atomicAdd(&cur[node], 1);
    csr[rbeg + p] = (int)(pe & 0xFFFFu);
  }
}

// ---- transform via MFMA: T = x @ Wt + bt, f16 out, col-sums to s1
__global__ __launch_bounds__(256) void k_transform_m(const float* __restrict__ x,
    const u16* __restrict__ wtT, const float* __restrict__ bt,
    u16* __restrict__ th, float* __restrict__ s1){
  __shared__ float sRed[8*NH];
  int tid = threadIdx.x;
  int w = tid >> 6, l = tid & 63;
  int lr = l & 15, kb = l >> 4;
  h8 bf[4][4];
  #pragma unroll
  for (int n = 0; n < 4; n++)
    #pragma unroll
    for (int kk = 0; kk < 4; kk++)
      bf[n][kk] = *(const h8*)&wtT[(size_t)(16*n + lr)*NF + kk*32 + kb*8];
  int node0 = blockIdx.x*64 + w*16;
  int rowA = node0 + lr; if (rowA > NN-1) rowA = NN-1;
  const float* xr = x + (size_t)rowA*NF + kb*8;
  f32x4 acc[4];
  #pragma unroll
  for (int n = 0; n < 4; n++) acc[n] = z4();
  #pragma unroll
  for (int kk = 0; kk < 4; kk++){
    float4 p = *(const float4*)(xr + kk*32);
    float4 q = *(const float4*)(xr + kk*32 + 4);
    h8 a = pack8(p, q);
    #pragma unroll
    for (int n = 0; n < 4; n++)
      acc[n] = __builtin_amdgcn_mfma_f32_16x16x32_f16(a, bf[n][kk], acc[n], 0, 0, 0);
  }
  #pragma unroll
  for (int n = 0; n < 4; n++){
    float bias = bt[16*n + lr];
    float a1 = 0.f, a2 = 0.f;
    #pragma unroll
    for (int r = 0; r < 4; r++){
      int g = node0 + 4*kb + r;
      float v = acc[n][r] + bias;
      if (g < NN){
        th[(size_t)g*NH + 16*n + lr] = f16b(v);
        a1 += v; a2 += v*v;
      }
    }
    a1 += __shfl_xor(a1, 16); a1 += __shfl_xor(a1, 32);
    a2 += __shfl_xor(a2, 16); a2 += __shfl_xor(a2, 32);
    if (kb == 0){
      sRed[w*NH + 16*n + lr] = a1;
      sRed[(4+w)*NH + 16*n + lr] = a2;
    }
  }
  __syncthreads();
  if (tid < NH){
    float a1 = sRed[tid] + sRed[NH+tid] + sRed[2*NH+tid] + sRed[3*NH+tid];
    float a2 = sRed[4*NH+tid] + sRed[5*NH+tid] + sRed[6*NH+tid] + sRed[7*NH+tid];
    unsafeAtomicAdd(&s1[tid], a1);
    unsafeAtomicAdd(&s1[NH+tid], a2);
  }
}

// ---- fused gather + MLP, 8 waves: csr slice in LDS, gather 8 nodes/wave,
// MLP split (row-block, col-half) across waves
__global__ __launch_bounds__(512) void k_gmlp(const u16* __restrict__ t,
    const int* __restrict__ rowptr, const int* __restrict__ csr, u16* __restrict__ Th,
    const u16* __restrict__ w1T, const u16* __restrict__ w2T, int wofs,
    const float* __restrict__ s1i,
    const void* __restrict__ gamma, const void* __restrict__ beta, int ofs,
    const int* __restrict__ flag, float* __restrict__ s1o){
  __shared__ __align__(16) u16 sU[64*NH];   // 8 KB, XOR-swizzled
  __shared__ __align__(16) u16 sV[64*NH];   // 8 KB, XOR-swizzled
  __shared__ float sRed[8*NH];              // 2 KB
  __shared__ float scs[NH], shs[NH];
  __shared__ int sCsr[CSR_LDS];             // 8 KB: block's contiguous csr slice
  __shared__ int sRp[65];
  int tid = threadIdx.x;
  int node0 = blockIdx.x*64;
  if (tid < NH){
    int bfl = flag[0];
    float gm = bfl ? bf1(((const u16*)gamma)[ofs+tid]) : ((const float*)gamma)[ofs+tid];
    float be = bfl ? bf1(((const u16*)beta)[ofs+tid])  : ((const float*)beta)[ofs+tid];
    float mean = s1i[tid] * (1.f/NN);
    float var  = s1i[NH+tid] * (1.f/NN) - mean*mean;
    float rr = rsqrtf(fmaxf(var, 0.f) + 1e-5f);
    float sc = gm * rr;
    scs[tid] = sc;
    shs[tid] = be - mean*sc;
  }
  if (tid >= 128 && tid < 193){            // rowptr slice (separate wave pair)
    int idx = tid - 128;
    int nd = node0 + idx;
    sRp[idx] = rowptr[nd > NN ? NN : nd];
  }
  __syncthreads();
  int base = sRp[0];
  int cnt = sRp[64] - base;
  for (int i = tid; i < cnt && i < CSR_LDS; i += 512) sCsr[i] = csr[base + i];
  __syncthreads();
  int w = tid >> 6, lane = tid & 63;
  int chunk = lane & 7, epar = lane >> 3;
  // ---- gather phase: wave w fills LDS rows w*8 .. w*8+7
  for (int idx = 0; idx < 8; idx++){
    int nl = w*8 + idx;
    int node = node0 + nl;
    int swz = (nl & 7) << 3;
    if (node < NN){
      int beg = sRp[nl], en = sRp[nl+1];
      float acc[8] = {0.f,0.f,0.f,0.f,0.f,0.f,0.f,0.f};
      if (epar == 0){
        uint4 q = *(const uint4*)&t[(size_t)node*NH + chunk*8];
        cv8h(q, acc);
      }
      int j = beg + epar;
      for (; j + 8 < en; j += 16){
        int o0 = j - base, o1 = o0 + 8;
        int src0 = (o0 < CSR_LDS) ? sCsr[o0] : csr[j];
        int src1 = (o1 < CSR_LDS) ? sCsr[o1] : csr[j+8];
        uint4 q0 = *(const uint4*)&t[(size_t)src0*NH + chunk*8];
        uint4 q1 = *(const uint4*)&t[(size_t)src1*NH + chunk*8];
        float f0[8], f1[8];
        cv8h(q0, f0);
        cv8h(q1, f1);
        #pragma unroll
        for (int i = 0; i < 8; i++) acc[i] += f0[i] + f1[i];
      }
      if (j < en){
        int o0 = j - base;
        int src = (o0 < CSR_LDS) ? sCsr[o0] : csr[j];
        uint4 q = *(const uint4*)&t[(size_t)src*NH + chunk*8];
        float f[8]; cv8h(q, f);
        #pragma unroll
        for (int i = 0; i < 8; i++) acc[i] += f[i];
      }
      #pragma unroll
      for (int i = 0; i < 8; i++){
        acc[i] += __shfl_xor(acc[i], 8);
        acc[i] += __shfl_xor(acc[i], 16);
        acc[i] += __shfl_xor(acc[i], 32);
      }
      if (epar == 0){
        float deg1 = (float)(en - beg + 1);
        float o[8];
        #pragma unroll
        for (int i = 0; i < 8; i++)
          o[i] = scs[chunk*8+i]*acc[i] + deg1*shs[chunk*8+i];
        uint4 ov;
        ov.x = pk(o[0], o[1]); ov.y = pk(o[2], o[3]);
        ov.z = pk(o[4], o[5]); ov.w = pk(o[6], o[7]);
        *(uint4*)&sU[nl*NH + ((chunk*8) ^ swz)] = ov;
      }
    } else if (epar == 0){
      uint4 zz; zz.x = 0; zz.y = 0; zz.z = 0; zz.w = 0;
      *(uint4*)&sU[nl*NH + ((chunk*8) ^ swz)] = zz;
    }
  }
  __syncthreads();
  // ---- MLP phase: wave w -> row-block rb = w&3, col-half ch = w>>2 (n = 2*ch+n2)
  int lr = lane & 15, kb = lane >> 4;
  int rb = w & 3, ch = w >> 2;
  h8 b1[2][2], b2[2][2];
  #pragma unroll
  for (int n2 = 0; n2 < 2; n2++)
    #pragma unroll
    for (int kk = 0; kk < 2; kk++){
      int n = 2*ch + n2;
      b1[n2][kk] = *(const h8*)&w1T[wofs + (16*n + lr)*NH + kk*32 + kb*8];
      b2[n2][kk] = *(const h8*)&w2T[wofs + (16*n + lr)*NH + kk*32 + kb*8];
    }
  int rv = 16*rb + lr;
  f32x4 acc[2];
  acc[0] = z4(); acc[1] = z4();
  const u16* urow = sU + rv*NH;
  #pragma unroll
  for (int kk = 0; kk < 2; kk++){
    h8 a = *(const h8*)&urow[(kk*32 + kb*8) ^ ((rv & 7) << 3)];
    #pragma unroll
    for (int n2 = 0; n2 < 2; n2++)
      acc[n2] = __builtin_amdgcn_mfma_f32_16x16x32_f16(a, b1[n2][kk], acc[n2], 0, 0, 0);
  }
  #pragma unroll
  for (int n2 = 0; n2 < 2; n2++){
    int n = 2*ch + n2;
    #pragma unroll
    for (int r = 0; r < 4; r++){
      int row = 16*rb + 4*kb + r;
      int col = 16*n + lr;
      sV[row*NH + (col ^ ((row & 7) << 3))] = f16b(fmaxf(acc[n2][r], 0.f));
    }
  }
  __syncthreads();
  f32x4 acc2[2];
  acc2[0] = z4(); acc2[1] = z4();
  const u16* vrow = sV + rv*NH;
  #pragma unroll
  for (int kk = 0; kk < 2; kk++){
    h8 a = *(const h8*)&vrow[(kk*32 + kb*8) ^ ((rv & 7) << 3)];
    #pragma unroll
    for (int n2 = 0; n2 < 2; n2++)
      acc2[n2] = __builtin_amdgcn_mfma_f32_16x16x32_f16(a, b2[n2][kk], acc2[n2], 0, 0, 0);
  }
  #pragma unroll
  for (int n2 = 0; n2 < 2; n2++){
    int n = 2*ch + n2;
    float a1 = 0.f, a2 = 0.f;
    #pragma unroll
    for (int r = 0; r < 4; r++){
      int g = node0 + 16*rb + 4*kb + r;
      float v = fmaxf(acc2[n2][r], 0.f);
      if (g < NN){
        Th[(size_t)g*NH + 16*n + lr] = f16b(v);
        a1 += v; a2 += v*v;
      }
    }
    a1 += __shfl_xor(a1, 16); a1 += __shfl_xor(a1, 32);
    a2 += __shfl_xor(a2, 16); a2 += __shfl_xor(a2, 32);
    if (kb == 0){
      sRed[rb*NH + 16*n + lr] = a1;        // ch halves write disjoint cols
      sRed[(4+rb)*NH + 16*n + lr] = a2;
    }
  }
  __syncthreads();
  if (tid < NH){
    float a1 = sRed[tid] + sRed[NH+tid] + sRed[2*NH+tid] + sRed[3*NH+tid];
    float a2 = sRed[4*NH+tid] + sRed[5*NH+tid] + sRed[6*NH+tid] + sRed[7*NH+tid];
    unsafeAtomicAdd(&s1o[tid], a1);
    unsafeAtomicAdd(&s1o[NH+tid], a2);
  }
}

// ---- per-graph embed with fused BN-fold (stats only); 512 threads for latency hiding
__global__ __launch_bounds__(512) void k_embed(const u16* __restrict__ t,
    const float* __restrict__ s1,
    const void* __restrict__ gamma, const void* __restrict__ beta, int ofs,
    const int* __restrict__ starts, const int* __restrict__ flag,
    void* __restrict__ dout, int layer){
  __shared__ float sRed[16*NH];
  int g = blockIdx.x;
  int tx = threadIdx.x & 63, ty = threadIdx.x >> 6;   // ty 0..7
  int bf = flag[0];
  float gm = bf ? bf1(((const u16*)gamma)[ofs+tx]) : ((const float*)gamma)[ofs+tx];
  float be = bf ? bf1(((const u16*)beta)[ofs+tx])  : ((const float*)beta)[ofs+tx];
  float mean = s1[tx] * (1.f/NN);
  float var  = s1[NH+tx] * (1.f/NN) - mean*mean;
  float rr = rsqrtf(fmaxf(var, 0.f) + 1e-5f);
  float sc = gm * rr;
  float sh = be - mean*sc;
  int st = starts[g], en = starts[g+1];
  float ls1 = 0.f, ls2 = 0.f;
  for (int n = st + ty; n < en; n += 8){
    float z = h1(t[(size_t)n*NH + tx]) * sc + sh;
    ls1 += z; ls2 += z*z;
  }
  sRed[ty*NH + tx] = ls1;
  sRed[(8+ty)*NH + tx] = ls2;
  __syncthreads();
  if (ty == 0){
    float a1 = 0.f, a2 = 0.f;
    #pragma unroll
    for (int r = 0; r < 8; r++){
      a1 += sRed[r*NH + tx];
      a2 += sRed[(8+r)*NH + tx];
    }
    int cnt = en - st;
    float inv = 1.f / (float)max(cnt, 1);
    float m = a1 * inv;
    float vv = a2 * inv - m*m;
    float s = sqrtf(fmaxf(vv, 0.f));
    size_t eidx = ((size_t)layer*NG + g)*NH + tx;
    size_t sidx = (size_t)4*NG*NH + eidx;
    if (bf){
      ((__hip_bfloat16*)dout)[eidx] = __float2bfloat16(m);
      ((__hip_bfloat16*)dout)[sidx] = __float2bfloat16(s);
    } else {
      ((float*)dout)[eidx] = m;
      ((float*)dout)[sidx] = s;
    }
  }
}

extern "C" void kernel_launch(void* const* d_in, const int* in_sizes, int n_in,
                              void* d_out, int out_size, void* d_ws, size_t ws_size,
                              hipStream_t stream) {
  const void* x    = d_in[0];
  const int* ei    = (const int*)d_in[1];
  const int* batch = (const int*)d_in[2];
  const void* Wt   = d_in[3];
  const void* bt   = d_in[4];
  const void* g0   = d_in[5];
  const void* b0   = d_in[6];
  const void* W1   = d_in[7];
  const void* W2   = d_in[8];
  const void* gs   = d_in[9];
  const void* bs   = d_in[10];

  u16*  tA    = (u16*)d_ws;                       // NN*NH f16 (double-buffered t)
  u16*  tB    = tA + (size_t)NN*NH;               // NN*NH f16
  float* sAll = (float*)(tB + (size_t)NN*NH);     // 4 stages x (s1[64], s2[64]) — zeroed
  int* bcount = (int*)(sAll + 512);               // 256 — zeroed
  int* ticket = bcount + NB;                      // 64 (pad) — zeroed
  int* bstart = ticket + 64;                      // 257 (pad to 288)
  int* bcur   = bstart + 288;                     // 256
  int* starts = bcur + NB;                        // 512
  int* flag   = starts + 512;                     // 64
  int* rowptr = flag + 64;                        // NN+64
  u32* pkE    = (u32*)(rowptr + NN + 64);         // NE packed (dst<<16|src)
  int* csr    = (int*)(pkE + NE);                 // NE
  u16* wtT    = (u16*)(csr + NE);                 // NH*NF f16 (16B-aligned)
  u16* w1T    = wtT + (size_t)NH*NF;              // 3*NH*NH f16
  u16* w2T    = w1T + (size_t)3*NH*NH;            // 3*NH*NH f16

  hipMemsetAsync(sAll, 0, (512 + NB + 64)*sizeof(float), stream);   // sAll + bcount + ticket
  k_init<<<49, 256, 0, stream>>>((const u32*)x, flag, batch, starts,
      (const float*)Wt, (const float*)W1, (const float*)W2, wtT, w1T, w2T);
  k_bhist<<<NBLK, 256, 0, stream>>>(ei, bcount, bstart, bcur, ticket);
  k_bscat<<<NBLK, 256, 0, stream>>>(ei, bcur, pkE);
  k_bfill<<<NB, 256, 0, stream>>>(pkE, bstart, rowptr, csr);

  k_transform_m<<<(NN+63)/64, 256, 0, stream>>>((const float*)x, wtT, (const float*)bt, tA, sAll);
  k_embed<<<NG, 512, 0, stream>>>(tA, sAll, g0, b0, 0, starts, flag, d_out, 0);

  u16* tin = tA;
  u16* tout = tB;
  for (int l = 0; l < 3; l++){
    float* sIn  = sAll + (size_t)l*128;
    float* sOut = sAll + (size_t)(l+1)*128;
    const void* gg = (l == 0) ? g0 : gs;
    const void* bb = (l == 0) ? b0 : bs;
    int ofs = (l == 0) ? 0 : (l-1)*NH;
    k_gmlp<<<(NN+63)/64, 512, 0, stream>>>(tin, rowptr, csr, tout, w1T, w2T, l*NH*NH,
        sIn, gg, bb, ofs, flag, sOut);
    k_embed<<<NG, 512, 0, stream>>>(tout, sOut, gs, bs, l*NH, starts, flag, d_out, l+1);
    u16* tmp = tin; tin = tout; tout = tmp;
  }
}